// Round 1
// baseline (892.029 us; speedup 1.0000x reference)
//
#include <hip/hip_runtime.h>

// Segment-sum scatter-add: out[row(e), f] += edge_w[e, f]
// One thread per (edge, 4-feature group): 16 threads/edge, float4 loads,
// 4 hardware fp32 atomics per thread.
__global__ __launch_bounds__(256) void GrCNetSpmm_scatter(
    const int* __restrict__ edge0,       // E row indices (edge[0,:])
    const float4* __restrict__ edge_w,   // E x 16 float4 (= E x 64 floats)
    float* __restrict__ out,             // N x 64
    int E)
{
    int t = blockIdx.x * blockDim.x + threadIdx.x;
    int total = E << 4;                  // E * 16 float4-groups
    if (t >= total) return;
    int e  = t >> 4;
    int fg = t & 15;
    int row = edge0[e];                  // broadcast across the 16 threads of this edge
    float4 w = edge_w[(size_t)e * 16 + fg];
    float* dst = out + (size_t)row * 64 + fg * 4;
    unsafeAtomicAdd(dst + 0, w.x);
    unsafeAtomicAdd(dst + 1, w.y);
    unsafeAtomicAdd(dst + 2, w.z);
    unsafeAtomicAdd(dst + 3, w.w);
}

extern "C" void kernel_launch(void* const* d_in, const int* in_sizes, int n_in,
                              void* d_out, int out_size, void* d_ws, size_t ws_size,
                              hipStream_t stream) {
    const int*   edge   = (const int*)d_in[0];     // (2, E) int32; edge[0] rows first
    const float* edge_w = (const float*)d_in[1];   // (E, 64) float32
    int E = in_sizes[1] / 64;

    // Output is poisoned to 0xAA before every timed launch — zero it.
    hipMemsetAsync(d_out, 0, (size_t)out_size * sizeof(float), stream);

    int total  = E * 16;
    int blocks = (total + 255) / 256;
    GrCNetSpmm_scatter<<<blocks, 256, 0, stream>>>(
        edge, (const float4*)edge_w, (float*)d_out, E);
}

// Round 2
// 537.947 us; speedup vs baseline: 1.6582x; 1.6582x over previous
//
#include <hip/hip_runtime.h>

// Segment-sum via counting-sort CSR + per-wave gather-reduce.
// Phases: (1) histogram rows, (2) single-block exclusive scan -> offsets,
// (3) scatter edge ids into CSR order, (4) one wave per row, lane = feature,
// registers accumulate, single coalesced write per output row.

__global__ __launch_bounds__(256) void hist_kernel(
    const int* __restrict__ edge0, int* __restrict__ counts, int E)
{
    int e = blockIdx.x * blockDim.x + threadIdx.x;
    if (e < E) atomicAdd(&counts[edge0[e]], 1);
}

__global__ __launch_bounds__(1024) void scan_kernel(
    const int* __restrict__ counts, int* __restrict__ offsets, int N, int Etot)
{
    __shared__ int buf[1024];
    __shared__ int carry;
    if (threadIdx.x == 0) carry = 0;
    __syncthreads();
    for (int base = 0; base < N; base += 1024) {
        int i = base + (int)threadIdx.x;
        int v = (i < N) ? counts[i] : 0;
        buf[threadIdx.x] = v;
        __syncthreads();
        // Hillis-Steele inclusive scan
        for (int off = 1; off < 1024; off <<= 1) {
            int t = (threadIdx.x >= (unsigned)off) ? buf[threadIdx.x - off] : 0;
            __syncthreads();
            buf[threadIdx.x] += t;
            __syncthreads();
        }
        int incl = buf[threadIdx.x];
        if (i < N) offsets[i] = carry + (incl - v);   // exclusive
        __syncthreads();
        if (threadIdx.x == 1023) carry += incl;       // tile total
        __syncthreads();
    }
    if (threadIdx.x == 0) offsets[N] = Etot;
}

__global__ __launch_bounds__(256) void scatter_kernel(
    const int* __restrict__ edge0, const int* __restrict__ offsets,
    int* __restrict__ cursor, int* __restrict__ ids, int E)
{
    int e = blockIdx.x * blockDim.x + threadIdx.x;
    if (e >= E) return;
    int row = edge0[e];
    int pos = offsets[row] + atomicAdd(&cursor[row], 1);
    ids[pos] = e;
}

// One 64-lane wave per row; lane = feature (F == 64).
__global__ __launch_bounds__(256) void reduce_kernel(
    const int* __restrict__ offsets, const int* __restrict__ ids,
    const float* __restrict__ edge_w, float* __restrict__ out, int N)
{
    int wave_in_block = threadIdx.x >> 6;           // 4 waves / block
    int lane = threadIdx.x & 63;
    int row = blockIdx.x * 4 + wave_in_block;
    if (row >= N) return;
    int beg = offsets[row];
    int end = offsets[row + 1];
    float acc = 0.f;
    for (int j = beg; j < end; ++j) {
        int e = ids[j];                              // broadcast load (same addr all lanes)
        acc += edge_w[(size_t)e * 64 + lane];        // wave reads 256B contiguous
    }
    out[(size_t)row * 64 + lane] = acc;              // every row written: no memset needed
}

extern "C" void kernel_launch(void* const* d_in, const int* in_sizes, int n_in,
                              void* d_out, int out_size, void* d_ws, size_t ws_size,
                              hipStream_t stream) {
    const int*   edge   = (const int*)d_in[0];     // (2,E) int32; rows = edge[0,:]
    const float* edge_w = (const float*)d_in[1];   // (E, 64) float32
    int E = in_sizes[0] / 2;
    int N = out_size / 64;

    // Workspace layout (int32): [counts N][cursor N][offsets N+1][ids E]
    int* counts  = (int*)d_ws;
    int* cursor  = counts + N;
    int* offsets = cursor + N;
    int* ids     = offsets + N + 1;

    hipMemsetAsync(counts, 0, (size_t)(2 * N) * sizeof(int), stream);  // counts+cursor

    int blocksE = (E + 255) / 256;
    hist_kernel<<<blocksE, 256, 0, stream>>>(edge, counts, E);
    scan_kernel<<<1, 1024, 0, stream>>>(counts, offsets, N, E);
    scatter_kernel<<<blocksE, 256, 0, stream>>>(edge, offsets, cursor, ids, E);

    int blocksR = (N + 3) / 4;                       // 4 rows (waves) per block
    reduce_kernel<<<blocksR, 256, 0, stream>>>(offsets, ids, edge_w, (float*)d_out, N);
}

// Round 4
// 386.152 us; speedup vs baseline: 2.3100x; 1.3931x over previous
//
#include <hip/hip_runtime.h>

// Segment-sum via counting-sort CSR + gather-reduce.
// CSR build: vectorized histogram -> 3-kernel hierarchical exclusive scan ->
// vectorized scatter (cursor = d2d copy of offsets).
// Reduce: 1 wave per row, 4 edges in flight per load (quarter-wave per edge,
// float4 per lane), unroll x2 => 8 independent edge_w loads outstanding.

#define TILE 1024  // scan tile: 256 threads x 4 elems

__global__ __launch_bounds__(256) void hist_kernel(
    const int* __restrict__ edge0, int* __restrict__ counts, int E)
{
    int t = blockIdx.x * blockDim.x + threadIdx.x;
    int base = t * 4;
    if (base + 3 < E) {
        int4 r = ((const int4*)edge0)[t];
        atomicAdd(&counts[r.x], 1);
        atomicAdd(&counts[r.y], 1);
        atomicAdd(&counts[r.z], 1);
        atomicAdd(&counts[r.w], 1);
    } else {
        for (int i = base; i < E; ++i) atomicAdd(&counts[edge0[i]], 1);
    }
}

__global__ __launch_bounds__(256) void scan_partial(
    const int* __restrict__ counts, int* __restrict__ tileSum, int N)
{
    __shared__ int wsum[4];
    int t = threadIdx.x;
    int base = blockIdx.x * TILE + t * 4;
    int s = 0;
    #pragma unroll
    for (int k = 0; k < 4; ++k) {
        int i = base + k;
        if (i < N) s += counts[i];
    }
    for (int off = 1; off < 64; off <<= 1) s += __shfl_xor(s, off);
    if ((t & 63) == 0) wsum[t >> 6] = s;
    __syncthreads();
    if (t == 0) tileSum[blockIdx.x] = wsum[0] + wsum[1] + wsum[2] + wsum[3];
}

// numTiles must be <= 64 (N <= 65536; here N = 50000 -> 49 tiles).
__global__ __launch_bounds__(64) void scan_tiles(
    const int* __restrict__ tileSum, int* __restrict__ tileOff, int numTiles,
    int* __restrict__ offsets, int N, int E)
{
    int t = threadIdx.x;
    int v0 = (t < numTiles) ? tileSum[t] : 0;
    int v = v0;
    for (int off = 1; off < 64; off <<= 1) {
        int u = __shfl_up(v, off);
        if (t >= off) v += u;
    }
    if (t < numTiles) tileOff[t] = v - v0;   // exclusive
    if (t == 0) offsets[N] = E;
}

__global__ __launch_bounds__(256) void scan_final(
    const int* __restrict__ counts, const int* __restrict__ tileOff,
    int* __restrict__ offsets, int N)
{
    __shared__ int wtot[4];
    int t = threadIdx.x;
    int lane = t & 63, wv = t >> 6;
    int base = blockIdx.x * TILE + t * 4;
    int c[4]; int s = 0;
    #pragma unroll
    for (int k = 0; k < 4; ++k) {
        int i = base + k;
        c[k] = (i < N) ? counts[i] : 0;
        s += c[k];
    }
    int inc = s;
    for (int off = 1; off < 64; off <<= 1) {
        int u = __shfl_up(inc, off);
        if (lane >= off) inc += u;
    }
    if (lane == 63) wtot[wv] = inc;
    __syncthreads();
    int wpre = 0;
    for (int w = 0; w < wv; ++w) wpre += wtot[w];
    int pre = tileOff[blockIdx.x] + wpre + (inc - s);
    #pragma unroll
    for (int k = 0; k < 4; ++k) {
        int i = base + k;
        if (i < N) offsets[i] = pre;
        pre += c[k];
    }
}

__global__ __launch_bounds__(256) void scatter_kernel(
    const int* __restrict__ edge0, int* __restrict__ cursor,
    int* __restrict__ ids, int E)
{
    int t = blockIdx.x * blockDim.x + threadIdx.x;
    int base = t * 4;
    if (base + 3 < E) {
        int4 r = ((const int4*)edge0)[t];
        ids[atomicAdd(&cursor[r.x], 1)] = base;
        ids[atomicAdd(&cursor[r.y], 1)] = base + 1;
        ids[atomicAdd(&cursor[r.z], 1)] = base + 2;
        ids[atomicAdd(&cursor[r.w], 1)] = base + 3;
    } else {
        for (int i = base; i < E; ++i) ids[atomicAdd(&cursor[edge0[i]], 1)] = i;
    }
}

// 1 wave per row. lane = 16*sub + q: sub selects one of 4 concurrent edges,
// q selects the float4 feature-group. Unroll x2 -> 8 edge_w loads in flight.
__global__ __launch_bounds__(256) void reduce_kernel(
    const int* __restrict__ offsets, const int* __restrict__ ids,
    const float4* __restrict__ w4, float4* __restrict__ out4, int N)
{
    int row = blockIdx.x * 4 + (threadIdx.x >> 6);
    if (row >= N) return;
    int lane = threadIdx.x & 63;
    int sub = lane >> 4, q = lane & 15;
    int beg = offsets[row], end = offsets[row + 1];
    float4 acc = make_float4(0.f, 0.f, 0.f, 0.f);
    int j = beg + sub;
    for (; j + 4 < end; j += 8) {
        int e0 = ids[j], e1 = ids[j + 4];
        float4 w0 = w4[(size_t)e0 * 16 + q];
        float4 w1 = w4[(size_t)e1 * 16 + q];
        acc.x += w0.x + w1.x; acc.y += w0.y + w1.y;
        acc.z += w0.z + w1.z; acc.w += w0.w + w1.w;
    }
    if (j < end) {
        int e = ids[j];
        float4 w = w4[(size_t)e * 16 + q];
        acc.x += w.x; acc.y += w.y; acc.z += w.z; acc.w += w.w;
    }
    acc.x += __shfl_xor(acc.x, 16); acc.y += __shfl_xor(acc.y, 16);
    acc.z += __shfl_xor(acc.z, 16); acc.w += __shfl_xor(acc.w, 16);
    acc.x += __shfl_xor(acc.x, 32); acc.y += __shfl_xor(acc.y, 32);
    acc.z += __shfl_xor(acc.z, 32); acc.w += __shfl_xor(acc.w, 32);
    if (sub == 0) out4[(size_t)row * 16 + q] = acc;
}

extern "C" void kernel_launch(void* const* d_in, const int* in_sizes, int n_in,
                              void* d_out, int out_size, void* d_ws, size_t ws_size,
                              hipStream_t stream) {
    const int*   edge   = (const int*)d_in[0];     // (2,E) int32; rows = edge[0,:]
    const float* edge_w = (const float*)d_in[1];   // (E, 64) float32
    int E = in_sizes[0] / 2;
    int N = out_size / 64;
    int numTiles = (N + TILE - 1) / TILE;          // 49 for N=50000 (must be <=64)

    // Workspace (int32): [counts N][offsets N+1][cursor N][ids E][tileSum 64][tileOff 64]
    int* counts  = (int*)d_ws;
    int* offsets = counts + N;
    int* cursor  = offsets + N + 1;
    int* ids     = cursor + N;
    int* tileSum = ids + E;
    int* tileOff = tileSum + 64;

    (void)hipMemsetAsync(counts, 0, (size_t)N * sizeof(int), stream);

    int blocksE = (E + 1023) / 1024;               // 4 edges per thread
    hist_kernel<<<blocksE, 256, 0, stream>>>(edge, counts, E);
    scan_partial<<<numTiles, 256, 0, stream>>>(counts, tileSum, N);
    scan_tiles<<<1, 64, 0, stream>>>(tileSum, tileOff, numTiles, offsets, N, E);
    scan_final<<<numTiles, 256, 0, stream>>>(counts, tileOff, offsets, N);
    (void)hipMemcpyAsync(cursor, offsets, (size_t)N * sizeof(int),
                         hipMemcpyDeviceToDevice, stream);
    scatter_kernel<<<blocksE, 256, 0, stream>>>(edge, cursor, ids, E);

    int blocksR = (N + 3) / 4;
    reduce_kernel<<<blocksR, 256, 0, stream>>>(offsets, ids, (const float4*)edge_w,
                                               (float4*)d_out, N);
}